// Round 2
// baseline (60630.334 us; speedup 1.0000x reference)
//
#include <hip/hip_runtime.h>
#include <hip/hip_bf16.h>

typedef _Float16 f16;
typedef unsigned short u16;
typedef unsigned char u8;
typedef __attribute__((ext_vector_type(8))) _Float16 f16x8;
typedef __attribute__((ext_vector_type(4))) float f32x4;

#define DI __device__ __forceinline__

constexpr int Bn = 128, Tn = 272, Cn = 96, Hn = 1024, Ln = 256;
constexpr int MELn = 26112, ZDn = 26368;
constexpr int OUT_SM = Bn * Tn * Cn;  // 3342336

DI float sigm(float x) { return 1.f / (1.f + expf(-x)); }
// Clamped narrowing: nothing can become inf/NaN.
DI f16 tof16(float x) { return (f16)fminf(fmaxf(x, -60000.f), 60000.f); }

// 4 fp32 -> 4 f16, 8B store.
DI void cvt4f(float4 v, f16* dst) {
  union { f16 o[4]; uint2 q; } t;
  t.o[0] = tof16(v.x); t.o[1] = tof16(v.y); t.o[2] = tof16(v.z); t.o[3] = tof16(v.w);
  *(uint2*)dst = t.q;
}

// ---- fp8 e4m3fn via bit math (y0 compression fallback for small ws) ----
DI u8 f32_to_e4m3(float x) {
  union { float f; unsigned u; } v; v.f = x;
  unsigned s = (v.u >> 31) << 7;
  float a = fabsf(x);
  if (!(a >= 0.015625f)) {              // subnormal / zero region (a < 2^-6)
    int m = (int)(a * 512.0f + 0.5f);   // ulp = 2^-9
    return (u8)(s | m);
  }
  if (a > 448.f) return (u8)(s | 0x7E);
  v.f = a;
  unsigned e = (v.u >> 23) & 0xFF;
  unsigned mant = (v.u & 0x7FFFFF) + (1u << 19);
  if (mant >> 23) { mant = 0; e += 1; }
  unsigned e8 = e - 120;
  return (u8)(s | (e8 << 3) | (mant >> 20));
}
DI float e4m3_to_f32(u8 b) {
  unsigned s = b >> 7, e = (b >> 3) & 15, m = b & 7;
  float v;
  if (e == 0) v = (float)m * 0.001953125f;
  else { union { unsigned u; float f; } t; t.u = ((e + 120) << 23) | (m << 20); v = t.f; }
  return s ? -v : v;
}

__global__ void melody_fill(const float* __restrict__ mel, f16* __restrict__ zcat) {
  int i = blockIdx.x * 256 + threadIdx.x;
  int b = blockIdx.y;
  if (i < MELn / 4)
    cvt4f(((const float4*)(mel + (size_t)b * MELn))[i],
          zcat + (size_t)b * ZDn + Ln + (size_t)i * 4);
}

__global__ void init_kernel(float* h0, float* h1, float* h2, float* h3,
                            f16* g0, f16* g1, f16* g2, f16* g3,
                            f16* xdec, const float* init_tok) {
  int i = blockIdx.x * 256 + threadIdx.x;
  if (i < Bn * Hn) {
    h0[i] = 0.f; h1[i] = 0.f; h2[i] = 0.f; h3[i] = 0.f;
    g0[i] = (f16)0.f; g1[i] = (f16)0.f; g2[i] = (f16)0.f; g3[i] = (f16)0.f;
  }
  if (i < Bn * Cn) {
    int b = i / Cn, c = i - b * Cn;
    xdec[b * 192 + c] = tof16(init_tok[c]);
  }
}

// One-shot: W16[3H][IX+Hn] = f16(concat(Wih, Whh)) row-major. Same tof16 as
// the per-step staging used to apply -> bit-identical GRU numerics.
// grid.x = 3072 (one block per gate-row), 256 threads.
__global__ void wconvert(const float* __restrict__ Wih, const float* __restrict__ Whh,
                         int IX, f16* __restrict__ W16) {
  const int KW = IX + Hn;
  const int row = blockIdx.x;
  const float* srcI = Wih + (size_t)row * IX;
  const float* srcH = Whh + (size_t)row * Hn;
  f16* dst = W16 + (size_t)row * KW;
  for (int j = threadIdx.x * 8; j < KW; j += 256 * 8) {
    const float* s = (j < IX) ? (srcI + j) : (srcH + (j - IX));  // IX%8==0: no straddle
    float4 v0 = *(const float4*)s, v1 = *(const float4*)(s + 4);
    union { f16 o[8]; uint4 q; } t;
    t.o[0] = tof16(v0.x); t.o[1] = tof16(v0.y); t.o[2] = tof16(v0.z); t.o[3] = tof16(v0.w);
    t.o[4] = tof16(v1.x); t.o[5] = tof16(v1.y); t.o[6] = tof16(v1.z); t.o[7] = tof16(v1.w);
    *(uint4*)(dst + j) = t.q;
  }
}

struct DirArgs {
  const void* x;      // XM=0: f16, XM=1: fp32, XM=2: fp8
  const float* Wih;   // raw fp32 weights (WM=0 path)
  const float* Whh;
  const f16* W16;     // preconverted concat weights (WM=1 path)
  const float* bih;
  const float* bhh;
  const float* hprev_f;
  const f16* hprev_h;
  float* hcur_f;
  f16* hcur_h;
  void* yout;   // layer-0 output base (already offset t*B*2048 + dir*H, in elts)
  int t;
};
struct StepArgs {
  DirArgs d[2];
  const int* length;  // null -> no masking (decoder)
  int xs;             // x row stride in ELEMENTS
};

// Fused GRU step: gates = x@Wih^T + h@Whh^T (+biases), n-gate split so
// n = tanh(i_n + r*h_n). 32 batch x 32 h-cols per block; 4 waves = 2x2
// quadrants of 16x16.
// XM: x dtype (0=f16,1=fp32,2=fp8). YM: y0 store (0=none,1=f16,2=fp8).
// WM: 0 = stage raw fp32 weights (legacy), 1 = preconverted f16 concat W16
//     with 16B chunks, hoisted addressing, and tile k+1 register prefetch
//     issued under tile k's MFMA (async-stage split).
template <int IX, int XM, int YM, int WM>
__global__ void __launch_bounds__(256) gru_step_kernel(StepArgs a) {
  constexpr int KT = (IX + Hn) / 32;   // IX % 32 == 0 for all instantiations
  constexpr int KW = IX + Hn;
  const DirArgs da = a.d[blockIdx.z];
  const int hc = blockIdx.x * 32;
  const int m0 = blockIdx.y * 32;
  const int tid = threadIdx.x;
  const int wave = tid >> 6, lane = tid & 63;
  const int mi = wave >> 1, ni = wave & 1;
  const int fr = lane & 15, fq = lane >> 4;

  __shared__ alignas(16) f16 lA[32 * 40];      // +8 pad: 16B-aligned, conflict-free
  __shared__ alignas(16) f16 lW[3][32 * 40];

  f32x4 accR = {0.f, 0.f, 0.f, 0.f};
  f32x4 accZ = accR, accIN = accR, accHN = accR;

  if (WM == 1) {
    // 512 16B chunks/tile: lo-128 threads stage A + gate1; hi-128 stage
    // gate0 + gate2. Wave-uniform lo/hi split; all addressing hoisted.
    const int idx0 = tid & 127;
    const int r0 = idx0 >> 2, ko0 = (idx0 & 3) * 8;
    const bool loA = (tid < 128);
    const f16* wbase0 = da.W16 + (size_t)((loA ? 1 : 0) * Hn + hc + r0) * KW + ko0;
    const f16* wbase1 = da.W16 + (size_t)(2 * Hn + hc + r0) * KW + ko0;  // hi only
    f16* dW0 = &lW[loA ? 1 : 0][0] + r0 * 40 + ko0;
    f16* dW1 = &lW[2][0] + r0 * 40 + ko0;
    f16* dA = lA + r0 * 40 + ko0;
    const f16* hrow = da.hprev_h + (size_t)(m0 + r0) * Hn;
    const f16* xrow_h = (const f16*)da.x + (size_t)(m0 + r0) * a.xs;
    const float* xrow_f = (const float*)da.x + (size_t)(m0 + r0) * a.xs;
    const u8* xrow_8 = (const u8*)da.x + (size_t)(m0 + r0) * a.xs;
    const f16* pA = lA + (mi * 16 + fr) * 40 + fq * 8;
    const f16* pW0 = &lW[0][0] + (ni * 16 + fr) * 40 + fq * 8;
    const f16* pW1 = &lW[1][0] + (ni * 16 + fr) * 40 + fq * 8;
    const f16* pW2 = &lW[2][0] + (ni * 16 + fr) * 40 + fq * 8;

    uint4 rA, rW0, rW1;
    float4 rx0, rx1;   // XM==1 x-part raw
    uint2 r8x;         // XM==2 x-part raw

    auto ldtile = [&](int kb) {
      const int kg = kb * 32 + ko0;
      if (loA) {
        if (kb * 32 < IX) {
          if (XM == 1) {
            rx0 = *(const float4*)(xrow_f + kg);
            rx1 = *(const float4*)(xrow_f + kg + 4);
          } else if (XM == 2) {
            r8x = *(const uint2*)(xrow_8 + kg);
          } else {
            rA = *(const uint4*)(xrow_h + kg);
          }
        } else {
          rA = *(const uint4*)(hrow + (kg - IX));
        }
        rW0 = *(const uint4*)(wbase0 + kb * 32);
      } else {
        rW0 = *(const uint4*)(wbase0 + kb * 32);
        rW1 = *(const uint4*)(wbase1 + kb * 32);
      }
    };
    auto sttile = [&](int kb) {
      if (loA) {
        if (kb * 32 < IX && XM == 1) {
          union { f16 o[8]; uint4 q; } t;
          t.o[0] = tof16(rx0.x); t.o[1] = tof16(rx0.y);
          t.o[2] = tof16(rx0.z); t.o[3] = tof16(rx0.w);
          t.o[4] = tof16(rx1.x); t.o[5] = tof16(rx1.y);
          t.o[6] = tof16(rx1.z); t.o[7] = tof16(rx1.w);
          *(uint4*)dA = t.q;
        } else if (kb * 32 < IX && XM == 2) {
          union { f16 o[8]; uint4 q; } t;
#pragma unroll
          for (int j = 0; j < 4; ++j) t.o[j] = (f16)e4m3_to_f32((u8)(r8x.x >> (8 * j)));
#pragma unroll
          for (int j = 0; j < 4; ++j) t.o[4 + j] = (f16)e4m3_to_f32((u8)(r8x.y >> (8 * j)));
          *(uint4*)dA = t.q;
        } else {
          *(uint4*)dA = rA;
        }
        *(uint4*)dW0 = rW0;
      } else {
        *(uint4*)dW0 = rW0;
        *(uint4*)dW1 = rW1;
      }
    };

    ldtile(0);
#pragma unroll 1
    for (int kb = 0; kb < KT; ++kb) {
      sttile(kb);
      __syncthreads();
      if (kb + 1 < KT) ldtile(kb + 1);   // prefetch under MFMA + barrier
      f16x8 af = *(const f16x8*)pA;
      f16x8 wr = *(const f16x8*)pW0;
      f16x8 wz = *(const f16x8*)pW1;
      f16x8 wn = *(const f16x8*)pW2;
      accR = __builtin_amdgcn_mfma_f32_16x16x32_f16(af, wr, accR, 0, 0, 0);
      accZ = __builtin_amdgcn_mfma_f32_16x16x32_f16(af, wz, accZ, 0, 0, 0);
      if (kb * 32 < IX)
        accIN = __builtin_amdgcn_mfma_f32_16x16x32_f16(af, wn, accIN, 0, 0, 0);
      else
        accHN = __builtin_amdgcn_mfma_f32_16x16x32_f16(af, wn, accHN, 0, 0, 0);
      __syncthreads();
    }
  } else {
    // ---- legacy fp32-weight staging path ----
#pragma unroll 1
    for (int kb = 0; kb < KT; ++kb) {
      const int k0 = kb * 32;
#pragma unroll
      for (int c = tid; c < 1024; c += 256) {
        const int region = c >> 8;          // 0=A, 1..3 = W gate streams
        const int idx = c & 255;
        const int r = idx >> 3;             // 0..31 row
        const int ko = (idx & 7) * 4;       // 0..28
        const int kg = k0 + ko;             // never straddles the IX boundary
        if (region == 0) {
          f16* dst = lA + r * 40 + ko;
          if (kg < IX) {
            if (XM == 1) {
              cvt4f(*(const float4*)((const float*)da.x + (size_t)(m0 + r) * a.xs + kg), dst);
            } else if (XM == 2) {
              unsigned r8 = *(const unsigned*)((const u8*)da.x + (size_t)(m0 + r) * a.xs + kg);
              union { f16 o[4]; uint2 q; } t;
#pragma unroll
              for (int j = 0; j < 4; ++j) t.o[j] = (f16)e4m3_to_f32((u8)(r8 >> (8 * j)));
              *(uint2*)dst = t.q;
            } else {
              *(uint2*)dst = *(const uint2*)((const f16*)da.x + (size_t)(m0 + r) * a.xs + kg);
            }
          } else {
            *(uint2*)dst = *(const uint2*)(da.hprev_h + (size_t)(m0 + r) * Hn + (kg - IX));
          }
        } else {
          const int g = region - 1;
          const int row = g * Hn + hc + r;
          const float* src = (kg < IX) ? (da.Wih + (size_t)row * IX + kg)
                                       : (da.Whh + (size_t)row * Hn + (kg - IX));
          cvt4f(*(const float4*)src, &lW[g][0] + r * 40 + ko);
        }
      }
      __syncthreads();
      f16x8 af = *(const f16x8*)(lA + (mi * 16 + fr) * 40 + fq * 8);
      f16x8 wr = *(const f16x8*)(&lW[0][0] + (ni * 16 + fr) * 40 + fq * 8);
      f16x8 wz = *(const f16x8*)(&lW[1][0] + (ni * 16 + fr) * 40 + fq * 8);
      f16x8 wn = *(const f16x8*)(&lW[2][0] + (ni * 16 + fr) * 40 + fq * 8);
      accR = __builtin_amdgcn_mfma_f32_16x16x32_f16(af, wr, accR, 0, 0, 0);
      accZ = __builtin_amdgcn_mfma_f32_16x16x32_f16(af, wz, accZ, 0, 0, 0);
      if (k0 < IX)
        accIN = __builtin_amdgcn_mfma_f32_16x16x32_f16(af, wn, accIN, 0, 0, 0);
      else
        accHN = __builtin_amdgcn_mfma_f32_16x16x32_f16(af, wn, accHN, 0, 0, 0);
      __syncthreads();
    }
  }

  const int k = hc + ni * 16 + fr;  // C/D: col(n)=lane&15, row(m)=(lane>>4)*4+reg
  const float br = da.bih[k] + da.bhh[k];
  const float bz = da.bih[Hn + k] + da.bhh[Hn + k];
  const float bin = da.bih[2 * Hn + k];
  const float bhn = da.bhh[2 * Hn + k];
#pragma unroll
  for (int r = 0; r < 4; ++r) {
    const int b = m0 + mi * 16 + fq * 4 + r;
    const float rg = sigm(accR[r] + br);
    const float zg = sigm(accZ[r] + bz);
    const float ng = tanhf(accIN[r] + bin + rg * (accHN[r] + bhn));
    const float hold = da.hprev_f[(size_t)b * Hn + k];
    const bool valid = (a.length == nullptr) || (da.t < a.length[b]);
    const float hnew = valid ? ((1.f - zg) * ng + zg * hold) : hold;
    da.hcur_f[(size_t)b * Hn + k] = hnew;
    da.hcur_h[(size_t)b * Hn + k] = tof16(hnew);
    if (YM == 1)
      ((f16*)da.yout)[(size_t)b * 2048 + k] = valid ? tof16(hnew) : (f16)0.f;
    else if (YM == 2)
      ((u8*)da.yout)[(size_t)b * 2048 + k] = f32_to_e4m3(valid ? hnew : 0.f);
  }
}

// Generic NT GEMM: C(128,N) = A(128,K) @ W^T + bias. A is internal f16; W is
// two stacked raw-fp32 blocks [W0 (nsplit rows); W1], converted in staging.
__global__ void __launch_bounds__(256) gemm_nt_kernel(
    const f16* __restrict__ A, const float* __restrict__ W0, const float* __restrict__ W1,
    const float* __restrict__ bias0, const float* __restrict__ bias1, int nsplit,
    float* __restrict__ Cout, int N, int K) {
  const int n0 = blockIdx.x * 64, m0 = blockIdx.y * 32;
  const int tid = threadIdx.x, wave = tid >> 6, lane = tid & 63;
  const int mi = wave >> 1, nj = wave & 1;
  const int fr = lane & 15, fq = lane >> 4;
  __shared__ alignas(16) f16 lA[32 * 40];
  __shared__ alignas(16) f16 lW[64 * 40];
  f32x4 acc0 = {0.f, 0.f, 0.f, 0.f}, acc1 = acc0;
  const int KT = K / 32;
#pragma unroll 1
  for (int kb = 0; kb < KT; ++kb) {
    const int k0 = kb * 32;
#pragma unroll
    for (int c = tid; c < 768; c += 256) {
      if (c < 256) {                       // A: 32 rows x 8 4-elt chunks
        int r = c >> 3, ko = (c & 7) * 4;
        *(uint2*)(lA + r * 40 + ko) =
            *(const uint2*)(A + (size_t)(m0 + r) * K + k0 + ko);
      } else {                             // W: 64 rows x 8 4-elt chunks
        int c2 = c - 256;
        int r = c2 >> 3, ko = (c2 & 7) * 4;
        int n = n0 + r;
        float4 v = {0.f, 0.f, 0.f, 0.f};
        if (n < N) {
          const float* src = (n < nsplit) ? (W0 + (size_t)n * K + k0 + ko)
                                          : (W1 + (size_t)(n - nsplit) * K + k0 + ko);
          v = *(const float4*)src;
        }
        cvt4f(v, lW + r * 40 + ko);
      }
    }
    __syncthreads();
    f16x8 af = *(const f16x8*)(lA + (mi * 16 + fr) * 40 + fq * 8);
    f16x8 w0 = *(const f16x8*)(lW + (nj * 32 + fr) * 40 + fq * 8);
    f16x8 w1 = *(const f16x8*)(lW + (nj * 32 + 16 + fr) * 40 + fq * 8);
    acc0 = __builtin_amdgcn_mfma_f32_16x16x32_f16(af, w0, acc0, 0, 0, 0);
    acc1 = __builtin_amdgcn_mfma_f32_16x16x32_f16(af, w1, acc1, 0, 0, 0);
    __syncthreads();
  }
#pragma unroll
  for (int j = 0; j < 2; ++j) {
    const f32x4 acc = j ? acc1 : acc0;
    const int n = n0 + nj * 32 + j * 16 + fr;
    if (n >= N) continue;
    const float bv = (n < nsplit) ? bias0[n] : bias1[n - nsplit];
#pragma unroll
    for (int r = 0; r < 4; ++r) {
      const int m = m0 + mi * 16 + fq * 4 + r;
      Cout[(size_t)m * N + n] = acc[r] + bv;
    }
  }
}

__global__ void build_hid(const f16* __restrict__ h0f, const f16* __restrict__ h0b,
                          const f16* __restrict__ h1f, const f16* __restrict__ h1b,
                          f16* __restrict__ hidf) {
  int i = blockIdx.x * 256 + threadIdx.x;
  if (i >= Bn * Hn) return;
  int b = i / Hn, k = i - b * Hn;
  f16* row = hidf + (size_t)b * 4096;
  row[k] = h0f[i];
  row[1024 + k] = h0b[i];
  row[2048 + k] = h1f[i];
  row[3072 + k] = h1b[i];
}

__global__ void z_kernel(const float* __restrict__ mulv, const float* __restrict__ eps,
                         f16* __restrict__ zcat, float* __restrict__ out_mu,
                         float* __restrict__ out_lv) {
  int i = blockIdx.x * 256 + threadIdx.x;
  if (i >= Bn * Ln) return;
  int b = i / Ln, j = i - b * Ln;
  float mu = mulv[(size_t)b * 512 + j];
  float lv = mulv[(size_t)b * 512 + 256 + j];
  float z = eps[i] * expf(0.5f * fminf(fmaxf(lv, -80.f), 80.f)) + mu;
  zcat[(size_t)b * ZDn + j] = tof16(z);
  out_mu[i] = mu;
  out_lv[i] = lv;
}

__global__ void zscatter(const float* __restrict__ zres, f16* __restrict__ xdec,
                         float* __restrict__ hdecf, f16* __restrict__ hdech) {
  int i = blockIdx.x * 256 + threadIdx.x;
  if (i >= Bn * 1120) return;
  int b = i / 1120, c = i - b * 1120;
  float v = zres[i];
  if (c < 96) {
    xdec[b * 192 + 96 + c] = tof16(v);
  } else {
    int k = c - 96;
    hdecf[(size_t)b * Hn + k] = v;
    hdech[(size_t)b * Hn + k] = tof16(v);
  }
}

// Logits stored fp32 directly into d_out's softmax region (overwritten
// in-place by softmax_kernel); argmax from fp32 LDS values.
__global__ void __launch_bounds__(256) outproj_kernel(
    const float* __restrict__ hdec, const float* __restrict__ Wout,
    const float* __restrict__ bout, float* __restrict__ logits,
    f16* __restrict__ xdec, int t) {
  const int b = blockIdx.x;
  const int tid = threadIdx.x, wave = tid >> 6, lane = tid & 63;
  __shared__ float hrow[Hn];
  __shared__ float chd[Cn];
  for (int i = tid; i < Hn; i += 256) hrow[i] = hdec[(size_t)b * Hn + i];
  __syncthreads();
  for (int n = wave; n < Cn; n += 4) {
    const float* wr = Wout + (size_t)n * Hn;
    float s = 0.f;
    for (int kk = lane; kk < Hn; kk += 64) s += hrow[kk] * wr[kk];
#pragma unroll
    for (int off = 32; off; off >>= 1) s += __shfl_down(s, off, 64);
    if (lane == 0) chd[n] = s + bout[n];
  }
  __syncthreads();
  float* lrow = logits + ((size_t)b * Tn + t) * Cn;
  for (int c = tid; c < Cn; c += 256) lrow[c] = chd[c];
  if (wave == 0) {
    float va = chd[lane];
    int ia = lane;
    if (lane < 32) {
      float vb = chd[64 + lane];
      if (vb > va) { va = vb; ia = 64 + lane; }
    }
#pragma unroll
    for (int off = 32; off; off >>= 1) {
      float vo = __shfl_down(va, off, 64);
      int io = __shfl_down(ia, off, 64);
      if (vo > va || (vo == va && io < ia)) { va = vo; ia = io; }
    }
    const int amax = __shfl(ia, 0, 64);  // first-occurrence argmax (np semantics)
    xdec[b * 192 + lane] = (f16)((lane == amax) ? 1.f : 0.f);
    if (lane < 32) xdec[b * 192 + 64 + lane] = (f16)((64 + lane == amax) ? 1.f : 0.f);
  }
}

__global__ void softmax_kernel(float* __restrict__ out) {
  const int row = blockIdx.x * 4 + (threadIdx.x >> 6);
  const int lane = threadIdx.x & 63;
  if (row >= Bn * Tn) return;
  float* lr = out + (size_t)row * Cn;    // fp32 logits, overwritten in place
  float v1 = lr[lane];
  float v2 = (lane < 32) ? lr[64 + lane] : -INFINITY;
  float m = fmaxf(v1, v2);
#pragma unroll
  for (int off = 32; off; off >>= 1) m = fmaxf(m, __shfl_xor(m, off, 64));
  float e1 = expf(v1 - m);
  float e2 = (lane < 32) ? expf(v2 - m) : 0.f;
  float s = e1 + e2;
#pragma unroll
  for (int off = 32; off; off >>= 1) s += __shfl_xor(s, off, 64);
  const float inv = 1.f / s, ls = logf(s);
  float* o1 = out + (size_t)OUT_SM + (size_t)row * Cn;
  lr[lane] = e1 * inv;
  o1[lane] = v1 - m - ls;
  if (lane < 32) {
    lr[64 + lane] = e2 * inv;
    o1[64 + lane] = v2 - m - ls;
  }
}

extern "C" void kernel_launch(void* const* d_in, const int* in_sizes, int n_in,
                              void* d_out, int out_size, void* d_ws, size_t ws_size,
                              hipStream_t stream) {
  (void)in_sizes; (void)n_in; (void)out_size;
  char* wsp = (char*)d_ws;
  size_t off = 0;
  auto alloc = [&](size_t bytes) -> void* {
    size_t o = (off + 255) & ~(size_t)255;
    off = o + bytes;
    return (void*)(wsp + o);
  };

  // Tier select on ws_size (constant per session -> graph-safe).
  const bool y16 = (ws_size >= 165000000ull);
  const size_t esz = y16 ? 2 : 1;      // y0 element bytes (f16 vs fp8 e4m3)

  char* y0 = (char*)alloc((size_t)Tn * Bn * 2048 * esz);   // ~136MB or ~68MB
  float* hf[5][2];
  f16* hh[5][2];
  for (int d = 0; d < 5; ++d)
    for (int p = 0; p < 2; ++p) {
      hf[d][p] = (float*)alloc((size_t)Bn * Hn * 4);
      hh[d][p] = (f16*)alloc((size_t)Bn * Hn * 2);
    }
  f16* zcat = (f16*)alloc((size_t)Bn * ZDn * 2);
  float* mulv_f = (float*)alloc((size_t)Bn * 512 * 4);
  float* zres_f = (float*)alloc((size_t)Bn * 1120 * 4);
  f16* hidf = (f16*)alloc((size_t)Bn * 4096 * 2);
  f16* xdec = (f16*)alloc((size_t)Bn * 192 * 2);

  // ---- f16 preconverted-weight cascade (space permitting; graph-safe:
  // decisions depend only on ws_size). Priority by per-step traffic:
  // e1 (37.7MB) > e0 (13.8MB) > dec (7.5MB).
  f16 *W16_e1f = nullptr, *W16_e1b = nullptr;
  f16 *W16_e0f = nullptr, *W16_e0b = nullptr;
  f16 *W16_dec = nullptr;
  auto try_allocw = [&](size_t elts) -> f16* {
    size_t o = (off + 255) & ~(size_t)255;
    if (o + elts * 2 > ws_size) return nullptr;
    off = o + elts * 2;
    return (f16*)(wsp + o);
  };
  {
    const size_t e1e = (size_t)3 * Hn * (2048 + Hn);
    const size_t e0e = (size_t)3 * Hn * (Cn + Hn);
    const size_t dce = (size_t)3 * Hn * (192 + Hn);
    size_t save = off;
    f16* a1 = try_allocw(e1e); f16* b1 = a1 ? try_allocw(e1e) : nullptr;
    if (b1) { W16_e1f = a1; W16_e1b = b1; } else off = save;
    save = off;
    f16* a0 = try_allocw(e0e); f16* b0 = a0 ? try_allocw(e0e) : nullptr;
    if (b0) { W16_e0f = a0; W16_e0b = b0; } else off = save;
    save = off;
    f16* dc = try_allocw(dce);
    if (dc) W16_dec = dc; else off = save;
  }
  if (W16_e1f) {
    wconvert<<<dim3(3072), dim3(256), 0, stream>>>(
        (const float*)d_in[11], (const float*)d_in[12], 2048, W16_e1f);
    wconvert<<<dim3(3072), dim3(256), 0, stream>>>(
        (const float*)d_in[15], (const float*)d_in[16], 2048, W16_e1b);
  }
  if (W16_e0f) {
    wconvert<<<dim3(3072), dim3(256), 0, stream>>>(
        (const float*)d_in[3], (const float*)d_in[4], Cn, W16_e0f);
    wconvert<<<dim3(3072), dim3(256), 0, stream>>>(
        (const float*)d_in[7], (const float*)d_in[8], Cn, W16_e0b);
  }
  if (W16_dec)
    wconvert<<<dim3(3072), dim3(256), 0, stream>>>(
        (const float*)d_in[28], (const float*)d_in[29], 192, W16_dec);

  init_kernel<<<dim3(512), dim3(256), 0, stream>>>(
      hf[0][0], hf[1][0], hf[2][0], hf[3][0],
      hh[0][0], hh[1][0], hh[2][0], hh[3][0],
      xdec, (const float*)d_in[27]);
  melody_fill<<<dim3((MELn / 4 + 255) / 256, Bn), dim3(256), 0, stream>>>(
      (const float*)d_in[1], zcat);

  const int* lenp = (const int*)d_in[34];

  // ---- encoder layer 0 (bidirectional, fused fwd+bwd per launch) ----
  for (int s = 0; s < Tn; ++s) {
    StepArgs a{};
    const int tf = s, tb = Tn - 1 - s;
    const int p = s & 1, q = (s + 1) & 1;
    a.d[0].x = (const float*)d_in[0] + (size_t)tf * Cn;
    a.d[0].Wih = (const float*)d_in[3]; a.d[0].Whh = (const float*)d_in[4];
    a.d[0].bih = (const float*)d_in[5]; a.d[0].bhh = (const float*)d_in[6];
    a.d[0].W16 = W16_e0f;
    a.d[0].hprev_f = hf[0][p]; a.d[0].hprev_h = hh[0][p];
    a.d[0].hcur_f = hf[0][q]; a.d[0].hcur_h = hh[0][q];
    a.d[0].yout = y0 + (size_t)tf * Bn * 2048 * esz;
    a.d[0].t = tf;
    a.d[1].x = (const float*)d_in[0] + (size_t)tb * Cn;
    a.d[1].Wih = (const float*)d_in[7]; a.d[1].Whh = (const float*)d_in[8];
    a.d[1].bih = (const float*)d_in[9]; a.d[1].bhh = (const float*)d_in[10];
    a.d[1].W16 = W16_e0b;
    a.d[1].hprev_f = hf[1][p]; a.d[1].hprev_h = hh[1][p];
    a.d[1].hcur_f = hf[1][q]; a.d[1].hcur_h = hh[1][q];
    a.d[1].yout = y0 + ((size_t)tb * Bn * 2048 + Hn) * esz;
    a.d[1].t = tb;
    a.length = lenp;
    a.xs = Tn * Cn;   // input_x is (B,T,C): batch stride T*C
    if (y16) {
      if (W16_e0f) gru_step_kernel<Cn, 1, 1, 1><<<dim3(32, 4, 2), dim3(256), 0, stream>>>(a);
      else         gru_step_kernel<Cn, 1, 1, 0><<<dim3(32, 4, 2), dim3(256), 0, stream>>>(a);
    } else {
      if (W16_e0f) gru_step_kernel<Cn, 1, 2, 1><<<dim3(32, 4, 2), dim3(256), 0, stream>>>(a);
      else         gru_step_kernel<Cn, 1, 2, 0><<<dim3(32, 4, 2), dim3(256), 0, stream>>>(a);
    }
  }
  // ---- encoder layer 1 ----
  for (int s = 0; s < Tn; ++s) {
    StepArgs a{};
    const int tf = s, tb = Tn - 1 - s;
    const int p = s & 1, q = (s + 1) & 1;
    a.d[0].x = y0 + (size_t)tf * Bn * 2048 * esz;
    a.d[0].Wih = (const float*)d_in[11]; a.d[0].Whh = (const float*)d_in[12];
    a.d[0].bih = (const float*)d_in[13]; a.d[0].bhh = (const float*)d_in[14];
    a.d[0].W16 = W16_e1f;
    a.d[0].hprev_f = hf[2][p]; a.d[0].hprev_h = hh[2][p];
    a.d[0].hcur_f = hf[2][q]; a.d[0].hcur_h = hh[2][q];
    a.d[0].yout = nullptr;
    a.d[0].t = tf;
    a.d[1].x = y0 + (size_t)tb * Bn * 2048 * esz;
    a.d[1].Wih = (const float*)d_in[15]; a.d[1].Whh = (const float*)d_in[16];
    a.d[1].bih = (const float*)d_in[17]; a.d[1].bhh = (const float*)d_in[18];
    a.d[1].W16 = W16_e1b;
    a.d[1].hprev_f = hf[3][p]; a.d[1].hprev_h = hh[3][p];
    a.d[1].hcur_f = hf[3][q]; a.d[1].hcur_h = hh[3][q];
    a.d[1].yout = nullptr;
    a.d[1].t = tb;
    a.length = lenp;
    a.xs = 2048;
    if (y16) {
      if (W16_e1f) gru_step_kernel<2048, 0, 0, 1><<<dim3(32, 4, 2), dim3(256), 0, stream>>>(a);
      else         gru_step_kernel<2048, 0, 0, 0><<<dim3(32, 4, 2), dim3(256), 0, stream>>>(a);
    } else {
      if (W16_e1f) gru_step_kernel<2048, 2, 0, 1><<<dim3(32, 4, 2), dim3(256), 0, stream>>>(a);
      else         gru_step_kernel<2048, 2, 0, 0><<<dim3(32, 4, 2), dim3(256), 0, stream>>>(a);
    }
  }

  // ---- VAE mid-section ----
  build_hid<<<dim3((Bn * Hn + 255) / 256), dim3(256), 0, stream>>>(
      hh[0][0], hh[1][0], hh[2][0], hh[3][0], hidf);
  gemm_nt_kernel<<<dim3(8, 4), dim3(256), 0, stream>>>(
      hidf, (const float*)d_in[19], (const float*)d_in[21],
      (const float*)d_in[20], (const float*)d_in[22], 256, mulv_f, 512, 4096);
  float* outp = (float*)d_out;
  z_kernel<<<dim3((Bn * Ln + 255) / 256), dim3(256), 0, stream>>>(
      mulv_f, (const float*)d_in[2], zcat,
      outp + 2 * (size_t)OUT_SM, outp + 2 * (size_t)OUT_SM + Bn * Ln);
  gemm_nt_kernel<<<dim3(18, 4), dim3(256), 0, stream>>>(
      zcat, (const float*)d_in[23], (const float*)d_in[25],
      (const float*)d_in[24], (const float*)d_in[26], 96, zres_f, 1120, ZDn);
  zscatter<<<dim3((Bn * 1120 + 255) / 256), dim3(256), 0, stream>>>(
      zres_f, xdec, hf[4][0], hh[4][0]);

  // ---- autoregressive decoder ----
  for (int s = 0; s < Tn; ++s) {
    StepArgs a{};
    const int p = s & 1, q = (s + 1) & 1;
    a.d[0].x = xdec;
    a.d[0].Wih = (const float*)d_in[28]; a.d[0].Whh = (const float*)d_in[29];
    a.d[0].bih = (const float*)d_in[30]; a.d[0].bhh = (const float*)d_in[31];
    a.d[0].W16 = W16_dec;
    a.d[0].hprev_f = hf[4][p]; a.d[0].hprev_h = hh[4][p];
    a.d[0].hcur_f = hf[4][q]; a.d[0].hcur_h = hh[4][q];
    a.d[0].yout = nullptr;
    a.d[0].t = s;
    a.d[1] = a.d[0];
    a.length = nullptr;  // decoder: no masking
    a.xs = 192;
    if (W16_dec) gru_step_kernel<192, 0, 0, 1><<<dim3(32, 4, 1), dim3(256), 0, stream>>>(a);
    else         gru_step_kernel<192, 0, 0, 0><<<dim3(32, 4, 1), dim3(256), 0, stream>>>(a);
    outproj_kernel<<<dim3(Bn), dim3(256), 0, stream>>>(
        hf[4][q], (const float*)d_in[32], (const float*)d_in[33],
        outp, xdec, s);
  }

  softmax_kernel<<<dim3((Bn * Tn + 3) / 4), dim3(256), 0, stream>>>(outp);
}

// Round 3
// 35789.508 us; speedup vs baseline: 1.6941x; 1.6941x over previous
//
#include <hip/hip_runtime.h>
#include <hip/hip_bf16.h>

typedef _Float16 f16;
typedef unsigned short u16;
typedef unsigned char u8;
typedef __attribute__((ext_vector_type(8))) _Float16 f16x8;
typedef __attribute__((ext_vector_type(4))) float f32x4;

#define DI __device__ __forceinline__

constexpr int Bn = 128, Tn = 272, Cn = 96, Hn = 1024, Ln = 256;
constexpr int MELn = 26112, ZDn = 26368;
constexpr int OUT_SM = Bn * Tn * Cn;  // 3342336

DI float sigm(float x) { return 1.f / (1.f + expf(-x)); }
// Clamped narrowing: nothing can become inf/NaN.
DI f16 tof16(float x) { return (f16)fminf(fmaxf(x, -60000.f), 60000.f); }

// 4 fp32 -> 4 f16, 8B store.
DI void cvt4f(float4 v, f16* dst) {
  union { f16 o[4]; uint2 q; } t;
  t.o[0] = tof16(v.x); t.o[1] = tof16(v.y); t.o[2] = tof16(v.z); t.o[3] = tof16(v.w);
  *(uint2*)dst = t.q;
}

// ---- fp8 e4m3fn via bit math (y0 compression fallback for small ws) ----
DI u8 f32_to_e4m3(float x) {
  union { float f; unsigned u; } v; v.f = x;
  unsigned s = (v.u >> 31) << 7;
  float a = fabsf(x);
  if (!(a >= 0.015625f)) {              // subnormal / zero region (a < 2^-6)
    int m = (int)(a * 512.0f + 0.5f);   // ulp = 2^-9
    return (u8)(s | m);
  }
  if (a > 448.f) return (u8)(s | 0x7E);
  v.f = a;
  unsigned e = (v.u >> 23) & 0xFF;
  unsigned mant = (v.u & 0x7FFFFF) + (1u << 19);
  if (mant >> 23) { mant = 0; e += 1; }
  unsigned e8 = e - 120;
  return (u8)(s | (e8 << 3) | (mant >> 20));
}
DI float e4m3_to_f32(u8 b) {
  unsigned s = b >> 7, e = (b >> 3) & 15, m = b & 7;
  float v;
  if (e == 0) v = (float)m * 0.001953125f;
  else { union { unsigned u; float f; } t; t.u = ((e + 120) << 23) | (m << 20); v = t.f; }
  return s ? -v : v;
}

__global__ void melody_fill(const float* __restrict__ mel, f16* __restrict__ zcat) {
  int i = blockIdx.x * 256 + threadIdx.x;
  int b = blockIdx.y;
  if (i < MELn / 4)
    cvt4f(((const float4*)(mel + (size_t)b * MELn))[i],
          zcat + (size_t)b * ZDn + Ln + (size_t)i * 4);
}

__global__ void init_kernel(float* h0, float* h1, float* h2, float* h3,
                            f16* g0, f16* g1, f16* g2, f16* g3,
                            f16* xdec, const float* init_tok) {
  int i = blockIdx.x * 256 + threadIdx.x;
  if (i < Bn * Hn) {
    h0[i] = 0.f; h1[i] = 0.f; h2[i] = 0.f; h3[i] = 0.f;
    g0[i] = (f16)0.f; g1[i] = (f16)0.f; g2[i] = (f16)0.f; g3[i] = (f16)0.f;
  }
  if (i < Bn * Cn) {
    int b = i / Cn, c = i - b * Cn;
    xdec[b * 192 + c] = tof16(init_tok[c]);
  }
}

// One-shot: W16[3H][KWP] = f16(concat(Wih, Whh)) row-major, zero-padded to
// KWP (multiple of 64). Same tof16 as staging -> bit-identical numerics.
// grid.x = 3072 (one block per gate-row), 256 threads.
__global__ void wconvert(const float* __restrict__ Wih, const float* __restrict__ Whh,
                         int IX, int KWP, f16* __restrict__ W16) {
  const int KW = IX + Hn;
  const int row = blockIdx.x;
  const float* srcI = Wih + (size_t)row * IX;
  const float* srcH = Whh + (size_t)row * Hn;
  f16* dst = W16 + (size_t)row * KWP;
  for (int j = threadIdx.x * 8; j < KWP; j += 256 * 8) {
    union { f16 o[8]; uint4 q; } t;
    if (j < KW) {  // IX%8==0, KW%8==0: chunks never straddle boundaries
      const float* s = (j < IX) ? (srcI + j) : (srcH + (j - IX));
      float4 v0 = *(const float4*)s, v1 = *(const float4*)(s + 4);
      t.o[0] = tof16(v0.x); t.o[1] = tof16(v0.y); t.o[2] = tof16(v0.z); t.o[3] = tof16(v0.w);
      t.o[4] = tof16(v1.x); t.o[5] = tof16(v1.y); t.o[6] = tof16(v1.z); t.o[7] = tof16(v1.w);
    } else {
      t.q = uint4{0, 0, 0, 0};
    }
    *(uint4*)(dst + j) = t.q;
  }
}

struct DirArgs {
  const void* x;      // XM=0: f16, XM=1: fp32, XM=2: fp8
  const float* Wih;   // raw fp32 weights (WM=0 path)
  const float* Whh;
  const f16* W16;     // preconverted concat weights, KWP-padded (WM=1 path)
  const float* bih;
  const float* bhh;
  const float* hprev_f;
  const f16* hprev_h;
  float* hcur_f;
  f16* hcur_h;
  void* yout;   // layer-0 output base (already offset t*B*2048 + dir*H, in elts)
  int t;
};
struct StepArgs {
  DirArgs d[2];
  const int* length;  // null -> no masking (decoder)
  int xs;             // x row stride in ELEMENTS
};

// Fused GRU step: gates = x@Wih^T + h@Whh^T (+biases), n-gate split so
// n = tanh(i_n + r*h_n). 32 batch x 32 h-cols per block.
// XM: x dtype (0=f16,1=fp32,2=fp8). YM: y0 store (0=none,1=f16,2=fp8).
// WM=0: legacy fp32-weight staging, 256 thr / 4 waves, 32-K steps.
// WM=1: preconverted f16 weights, 512 thr / 8 waves, 64-K steps with the
//       K-slice split across wave pairs (ki), partials reduced via LDS.
//       Register prefetch of step it+1 issued under step it's MFMA.
template <int IX, int XM, int YM, int WM>
__global__ void __launch_bounds__(WM == 1 ? 512 : 256) gru_step_kernel(StepArgs a) {
  constexpr int KW = IX + Hn;
  constexpr int KWP = (KW + 63) & ~63;
  constexpr int KT = KW / 32;          // legacy 32-K step count (KW%32==0)
  constexpr int NT = KWP / 64;         // WM1 64-K step count
  const DirArgs da = a.d[blockIdx.z];
  const int hc = blockIdx.x * 32;
  const int m0 = blockIdx.y * 32;
  const int tid = threadIdx.x;
  const int wave = tid >> 6, lane = tid & 63;
  const int ki = wave >> 2;            // 0 for WM0 (4 waves)
  const int mi = (wave >> 1) & 1, ni = wave & 1;
  const int fr = lane & 15, fq = lane >> 4;

  // WM1: 72-stride (64-K + 8 pad). Legacy path uses 40-stride inside the
  // same arrays (both staging and reads -> consistent).
  __shared__ alignas(16) f16 lA[32 * 72];
  __shared__ alignas(16) f16 lW[3][32 * 72];

  f32x4 accR = {0.f, 0.f, 0.f, 0.f};
  f32x4 accZ = accR, accIN = accR, accHN = accR;

  if constexpr (WM == 1) {
    // 1024 16B chunks per 64-K step, 2 per thread:
    //   chunk0 = tid       : A (tid<256) | gate0 weights (tid>=256)
    //   chunk1 = tid + 512 : gate1       | gate2
    const int idx0 = tid & 255;
    const int r0 = idx0 >> 3;            // 0..31 row
    const int ko0 = (idx0 & 7) * 8;      // 0..56 (f16 col within 64)
    const bool loA = (tid < 256);
    const f16* wb0 = da.W16 + (size_t)(hc + r0) * KWP + ko0;                   // gate0 (!loA)
    const f16* wb1 = da.W16 + (size_t)((loA ? 1 : 2) * Hn + hc + r0) * KWP + ko0;
    f16* d0 = loA ? (lA + r0 * 72 + ko0) : (&lW[0][0] + r0 * 72 + ko0);
    f16* d1 = &lW[loA ? 1 : 2][0] + r0 * 72 + ko0;
    const f16* hrow = da.hprev_h + (size_t)(m0 + r0) * Hn;
    const f16* xrow_h = (const f16*)da.x + (size_t)(m0 + r0) * a.xs;
    const float* xrow_f = (const float*)da.x + (size_t)(m0 + r0) * a.xs;
    const u8* xrow_8 = (const u8*)da.x + (size_t)(m0 + r0) * a.xs;
    const f16* pA = lA + (mi * 16 + fr) * 72 + ki * 32 + fq * 8;
    const f16* pW0 = &lW[0][0] + (ni * 16 + fr) * 72 + ki * 32 + fq * 8;
    const f16* pW1 = &lW[1][0] + (ni * 16 + fr) * 72 + ki * 32 + fq * 8;
    const f16* pW2 = &lW[2][0] + (ni * 16 + fr) * 72 + ki * 32 + fq * 8;

    uint4 rA{0, 0, 0, 0}, r1{0, 0, 0, 0};
    float4 rx0, rx1;   // XM==1 x-part raw
    uint2 r8x;         // XM==2 x-part raw

    auto ldtile = [&](int it) {
      const int kg = it * 64 + ko0;
      if (loA) {
        if (kg < IX) {
          if (XM == 1) {
            rx0 = *(const float4*)(xrow_f + kg);
            rx1 = *(const float4*)(xrow_f + kg + 4);
          } else if (XM == 2) {
            r8x = *(const uint2*)(xrow_8 + kg);
          } else {
            rA = *(const uint4*)(xrow_h + kg);
          }
        } else if (kg < KW) {
          rA = *(const uint4*)(hrow + (kg - IX));
        } else {
          rA = uint4{0, 0, 0, 0};        // zero-pad tail
        }
      } else {
        rA = *(const uint4*)(wb0 + it * 64);
      }
      r1 = *(const uint4*)(wb1 + it * 64);
    };
    auto sttile = [&](int it) {
      const int kg = it * 64 + ko0;
      if (loA && XM == 1 && kg < IX) {
        union { f16 o[8]; uint4 q; } t;
        t.o[0] = tof16(rx0.x); t.o[1] = tof16(rx0.y);
        t.o[2] = tof16(rx0.z); t.o[3] = tof16(rx0.w);
        t.o[4] = tof16(rx1.x); t.o[5] = tof16(rx1.y);
        t.o[6] = tof16(rx1.z); t.o[7] = tof16(rx1.w);
        *(uint4*)d0 = t.q;
      } else if (loA && XM == 2 && kg < IX) {
        union { f16 o[8]; uint4 q; } t;
#pragma unroll
        for (int j = 0; j < 4; ++j) t.o[j] = (f16)e4m3_to_f32((u8)(r8x.x >> (8 * j)));
#pragma unroll
        for (int j = 0; j < 4; ++j) t.o[4 + j] = (f16)e4m3_to_f32((u8)(r8x.y >> (8 * j)));
        *(uint4*)d0 = t.q;
      } else {
        *(uint4*)d0 = rA;
      }
      *(uint4*)d1 = r1;
    };

    ldtile(0);
#pragma unroll 1
    for (int it = 0; it < NT; ++it) {
      sttile(it);
      __syncthreads();
      if (it + 1 < NT) ldtile(it + 1);   // prefetch under MFMA + barrier
      f16x8 af = *(const f16x8*)pA;
      f16x8 wr = *(const f16x8*)pW0;
      f16x8 wz = *(const f16x8*)pW1;
      f16x8 wn = *(const f16x8*)pW2;
      accR = __builtin_amdgcn_mfma_f32_16x16x32_f16(af, wr, accR, 0, 0, 0);
      accZ = __builtin_amdgcn_mfma_f32_16x16x32_f16(af, wz, accZ, 0, 0, 0);
      const int kgw = it * 64 + ki * 32;  // wave-uniform
      if (kgw < IX)
        accIN = __builtin_amdgcn_mfma_f32_16x16x32_f16(af, wn, accIN, 0, 0, 0);
      else
        accHN = __builtin_amdgcn_mfma_f32_16x16x32_f16(af, wn, accHN, 0, 0, 0);
      __syncthreads();
    }
  } else {
    // ---- legacy fp32-weight staging path (256 threads) ----
#pragma unroll 1
    for (int kb = 0; kb < KT; ++kb) {
      const int k0 = kb * 32;
#pragma unroll
      for (int c = tid; c < 1024; c += 256) {
        const int region = c >> 8;          // 0=A, 1..3 = W gate streams
        const int idx = c & 255;
        const int r = idx >> 3;             // 0..31 row
        const int ko = (idx & 7) * 4;       // 0..28
        const int kg = k0 + ko;             // never straddles the IX boundary
        if (region == 0) {
          f16* dst = lA + r * 40 + ko;
          if (kg < IX) {
            if (XM == 1) {
              cvt4f(*(const float4*)((const float*)da.x + (size_t)(m0 + r) * a.xs + kg), dst);
            } else if (XM == 2) {
              unsigned r8 = *(const unsigned*)((const u8*)da.x + (size_t)(m0 + r) * a.xs + kg);
              union { f16 o[4]; uint2 q; } t;
#pragma unroll
              for (int j = 0; j < 4; ++j) t.o[j] = (f16)e4m3_to_f32((u8)(r8 >> (8 * j)));
              *(uint2*)dst = t.q;
            } else {
              *(uint2*)dst = *(const uint2*)((const f16*)da.x + (size_t)(m0 + r) * a.xs + kg);
            }
          } else {
            *(uint2*)dst = *(const uint2*)(da.hprev_h + (size_t)(m0 + r) * Hn + (kg - IX));
          }
        } else {
          const int g = region - 1;
          const int row = g * Hn + hc + r;
          const float* src = (kg < IX) ? (da.Wih + (size_t)row * IX + kg)
                                       : (da.Whh + (size_t)row * Hn + (kg - IX));
          cvt4f(*(const float4*)src, &lW[g][0] + r * 40 + ko);
        }
      }
      __syncthreads();
      f16x8 af = *(const f16x8*)(lA + (mi * 16 + fr) * 40 + fq * 8);
      f16x8 wr = *(const f16x8*)(&lW[0][0] + (ni * 16 + fr) * 40 + fq * 8);
      f16x8 wz = *(const f16x8*)(&lW[1][0] + (ni * 16 + fr) * 40 + fq * 8);
      f16x8 wn = *(const f16x8*)(&lW[2][0] + (ni * 16 + fr) * 40 + fq * 8);
      accR = __builtin_amdgcn_mfma_f32_16x16x32_f16(af, wr, accR, 0, 0, 0);
      accZ = __builtin_amdgcn_mfma_f32_16x16x32_f16(af, wz, accZ, 0, 0, 0);
      if (k0 < IX)
        accIN = __builtin_amdgcn_mfma_f32_16x16x32_f16(af, wn, accIN, 0, 0, 0);
      else
        accHN = __builtin_amdgcn_mfma_f32_16x16x32_f16(af, wn, accHN, 0, 0, 0);
      __syncthreads();
    }
  }

  if constexpr (WM == 1) {
    // Reduce ki=1 partials into ki=0 waves (wave w pairs with w+4: same mi,ni).
    __shared__ f32x4 red[4][64][4];
    if (ki == 1) {
      red[wave & 3][lane][0] = accR;
      red[wave & 3][lane][1] = accZ;
      red[wave & 3][lane][2] = accIN;
      red[wave & 3][lane][3] = accHN;
    }
    __syncthreads();
    if (ki == 1) return;
    accR += red[wave & 3][lane][0];
    accZ += red[wave & 3][lane][1];
    accIN += red[wave & 3][lane][2];
    accHN += red[wave & 3][lane][3];
  }

  const int k = hc + ni * 16 + fr;  // C/D: col(n)=lane&15, row(m)=(lane>>4)*4+reg
  const float br = da.bih[k] + da.bhh[k];
  const float bz = da.bih[Hn + k] + da.bhh[Hn + k];
  const float bin = da.bih[2 * Hn + k];
  const float bhn = da.bhh[2 * Hn + k];
#pragma unroll
  for (int r = 0; r < 4; ++r) {
    const int b = m0 + mi * 16 + fq * 4 + r;
    const float rg = sigm(accR[r] + br);
    const float zg = sigm(accZ[r] + bz);
    const float ng = tanhf(accIN[r] + bin + rg * (accHN[r] + bhn));
    const float hold = da.hprev_f[(size_t)b * Hn + k];
    const bool valid = (a.length == nullptr) || (da.t < a.length[b]);
    const float hnew = valid ? ((1.f - zg) * ng + zg * hold) : hold;
    da.hcur_f[(size_t)b * Hn + k] = hnew;
    da.hcur_h[(size_t)b * Hn + k] = tof16(hnew);
    if (YM == 1)
      ((f16*)da.yout)[(size_t)b * 2048 + k] = valid ? tof16(hnew) : (f16)0.f;
    else if (YM == 2)
      ((u8*)da.yout)[(size_t)b * 2048 + k] = f32_to_e4m3(valid ? hnew : 0.f);
  }
}

// Generic NT GEMM: C(128,N) = A(128,K) @ W^T + bias. A is internal f16; W is
// two stacked raw-fp32 blocks [W0 (nsplit rows); W1], converted in staging.
__global__ void __launch_bounds__(256) gemm_nt_kernel(
    const f16* __restrict__ A, const float* __restrict__ W0, const float* __restrict__ W1,
    const float* __restrict__ bias0, const float* __restrict__ bias1, int nsplit,
    float* __restrict__ Cout, int N, int K) {
  const int n0 = blockIdx.x * 64, m0 = blockIdx.y * 32;
  const int tid = threadIdx.x, wave = tid >> 6, lane = tid & 63;
  const int mi = wave >> 1, nj = wave & 1;
  const int fr = lane & 15, fq = lane >> 4;
  __shared__ alignas(16) f16 lA[32 * 40];
  __shared__ alignas(16) f16 lW[64 * 40];
  f32x4 acc0 = {0.f, 0.f, 0.f, 0.f}, acc1 = acc0;
  const int KT = K / 32;
#pragma unroll 1
  for (int kb = 0; kb < KT; ++kb) {
    const int k0 = kb * 32;
#pragma unroll
    for (int c = tid; c < 768; c += 256) {
      if (c < 256) {                       // A: 32 rows x 8 4-elt chunks
        int r = c >> 3, ko = (c & 7) * 4;
        *(uint2*)(lA + r * 40 + ko) =
            *(const uint2*)(A + (size_t)(m0 + r) * K + k0 + ko);
      } else {                             // W: 64 rows x 8 4-elt chunks
        int c2 = c - 256;
        int r = c2 >> 3, ko = (c2 & 7) * 4;
        int n = n0 + r;
        float4 v = {0.f, 0.f, 0.f, 0.f};
        if (n < N) {
          const float* src = (n < nsplit) ? (W0 + (size_t)n * K + k0 + ko)
                                          : (W1 + (size_t)(n - nsplit) * K + k0 + ko);
          v = *(const float4*)src;
        }
        cvt4f(v, lW + r * 40 + ko);
      }
    }
    __syncthreads();
    f16x8 af = *(const f16x8*)(lA + (mi * 16 + fr) * 40 + fq * 8);
    f16x8 w0 = *(const f16x8*)(lW + (nj * 32 + fr) * 40 + fq * 8);
    f16x8 w1 = *(const f16x8*)(lW + (nj * 32 + 16 + fr) * 40 + fq * 8);
    acc0 = __builtin_amdgcn_mfma_f32_16x16x32_f16(af, w0, acc0, 0, 0, 0);
    acc1 = __builtin_amdgcn_mfma_f32_16x16x32_f16(af, w1, acc1, 0, 0, 0);
    __syncthreads();
  }
#pragma unroll
  for (int j = 0; j < 2; ++j) {
    const f32x4 acc = j ? acc1 : acc0;
    const int n = n0 + nj * 32 + j * 16 + fr;
    if (n >= N) continue;
    const float bv = (n < nsplit) ? bias0[n] : bias1[n - nsplit];
#pragma unroll
    for (int r = 0; r < 4; ++r) {
      const int m = m0 + mi * 16 + fq * 4 + r;
      Cout[(size_t)m * N + n] = acc[r] + bv;
    }
  }
}

__global__ void build_hid(const f16* __restrict__ h0f, const f16* __restrict__ h0b,
                          const f16* __restrict__ h1f, const f16* __restrict__ h1b,
                          f16* __restrict__ hidf) {
  int i = blockIdx.x * 256 + threadIdx.x;
  if (i >= Bn * Hn) return;
  int b = i / Hn, k = i - b * Hn;
  f16* row = hidf + (size_t)b * 4096;
  row[k] = h0f[i];
  row[1024 + k] = h0b[i];
  row[2048 + k] = h1f[i];
  row[3072 + k] = h1b[i];
}

__global__ void z_kernel(const float* __restrict__ mulv, const float* __restrict__ eps,
                         f16* __restrict__ zcat, float* __restrict__ out_mu,
                         float* __restrict__ out_lv) {
  int i = blockIdx.x * 256 + threadIdx.x;
  if (i >= Bn * Ln) return;
  int b = i / Ln, j = i - b * Ln;
  float mu = mulv[(size_t)b * 512 + j];
  float lv = mulv[(size_t)b * 512 + 256 + j];
  float z = eps[i] * expf(0.5f * fminf(fmaxf(lv, -80.f), 80.f)) + mu;
  zcat[(size_t)b * ZDn + j] = tof16(z);
  out_mu[i] = mu;
  out_lv[i] = lv;
}

__global__ void zscatter(const float* __restrict__ zres, f16* __restrict__ xdec,
                         float* __restrict__ hdecf, f16* __restrict__ hdech) {
  int i = blockIdx.x * 256 + threadIdx.x;
  if (i >= Bn * 1120) return;
  int b = i / 1120, c = i - b * 1120;
  float v = zres[i];
  if (c < 96) {
    xdec[b * 192 + 96 + c] = tof16(v);
  } else {
    int k = c - 96;
    hdecf[(size_t)b * Hn + k] = v;
    hdech[(size_t)b * Hn + k] = tof16(v);
  }
}

// Logits stored fp32 directly into d_out's softmax region (overwritten
// in-place by softmax_kernel); argmax from fp32 LDS values.
__global__ void __launch_bounds__(256) outproj_kernel(
    const float* __restrict__ hdec, const float* __restrict__ Wout,
    const float* __restrict__ bout, float* __restrict__ logits,
    f16* __restrict__ xdec, int t) {
  const int b = blockIdx.x;
  const int tid = threadIdx.x, wave = tid >> 6, lane = tid & 63;
  __shared__ float hrow[Hn];
  __shared__ float chd[Cn];
  for (int i = tid; i < Hn; i += 256) hrow[i] = hdec[(size_t)b * Hn + i];
  __syncthreads();
  for (int n = wave; n < Cn; n += 4) {
    const float* wr = Wout + (size_t)n * Hn;
    float s = 0.f;
    for (int kk = lane; kk < Hn; kk += 64) s += hrow[kk] * wr[kk];
#pragma unroll
    for (int off = 32; off; off >>= 1) s += __shfl_down(s, off, 64);
    if (lane == 0) chd[n] = s + bout[n];
  }
  __syncthreads();
  float* lrow = logits + ((size_t)b * Tn + t) * Cn;
  for (int c = tid; c < Cn; c += 256) lrow[c] = chd[c];
  if (wave == 0) {
    float va = chd[lane];
    int ia = lane;
    if (lane < 32) {
      float vb = chd[64 + lane];
      if (vb > va) { va = vb; ia = 64 + lane; }
    }
#pragma unroll
    for (int off = 32; off; off >>= 1) {
      float vo = __shfl_down(va, off, 64);
      int io = __shfl_down(ia, off, 64);
      if (vo > va || (vo == va && io < ia)) { va = vo; ia = io; }
    }
    const int amax = __shfl(ia, 0, 64);  // first-occurrence argmax (np semantics)
    xdec[b * 192 + lane] = (f16)((lane == amax) ? 1.f : 0.f);
    if (lane < 32) xdec[b * 192 + 64 + lane] = (f16)((64 + lane == amax) ? 1.f : 0.f);
  }
}

__global__ void softmax_kernel(float* __restrict__ out) {
  const int row = blockIdx.x * 4 + (threadIdx.x >> 6);
  const int lane = threadIdx.x & 63;
  if (row >= Bn * Tn) return;
  float* lr = out + (size_t)row * Cn;    // fp32 logits, overwritten in place
  float v1 = lr[lane];
  float v2 = (lane < 32) ? lr[64 + lane] : -INFINITY;
  float m = fmaxf(v1, v2);
#pragma unroll
  for (int off = 32; off; off >>= 1) m = fmaxf(m, __shfl_xor(m, off, 64));
  float e1 = expf(v1 - m);
  float e2 = (lane < 32) ? expf(v2 - m) : 0.f;
  float s = e1 + e2;
#pragma unroll
  for (int off = 32; off; off >>= 1) s += __shfl_xor(s, off, 64);
  const float inv = 1.f / s, ls = logf(s);
  float* o1 = out + (size_t)OUT_SM + (size_t)row * Cn;
  lr[lane] = e1 * inv;
  o1[lane] = v1 - m - ls;
  if (lane < 32) {
    lr[64 + lane] = e2 * inv;
    o1[64 + lane] = v2 - m - ls;
  }
}

extern "C" void kernel_launch(void* const* d_in, const int* in_sizes, int n_in,
                              void* d_out, int out_size, void* d_ws, size_t ws_size,
                              hipStream_t stream) {
  (void)in_sizes; (void)n_in; (void)out_size;
  char* wsp = (char*)d_ws;
  size_t off = 0;
  auto alloc = [&](size_t bytes) -> void* {
    size_t o = (off + 255) & ~(size_t)255;
    off = o + bytes;
    return (void*)(wsp + o);
  };

  // Tier select on ws_size (constant per session -> graph-safe).
  const bool y16 = (ws_size >= 165000000ull);
  const size_t esz = y16 ? 2 : 1;      // y0 element bytes (f16 vs fp8 e4m3)

  char* y0 = (char*)alloc((size_t)Tn * Bn * 2048 * esz);   // ~136MB or ~68MB
  float* hf[5][2];
  f16* hh[5][2];
  for (int d = 0; d < 5; ++d)
    for (int p = 0; p < 2; ++p) {
      hf[d][p] = (float*)alloc((size_t)Bn * Hn * 4);
      hh[d][p] = (f16*)alloc((size_t)Bn * Hn * 2);
    }
  f16* zcat = (f16*)alloc((size_t)Bn * ZDn * 2);
  float* mulv_f = (float*)alloc((size_t)Bn * 512 * 4);
  float* zres_f = (float*)alloc((size_t)Bn * 1120 * 4);
  f16* hidf = (f16*)alloc((size_t)Bn * 4096 * 2);
  f16* xdec = (f16*)alloc((size_t)Bn * 192 * 2);

  // ---- f16 preconverted-weight cascade (space permitting; graph-safe:
  // decisions depend only on ws_size). KWP-padded rows (mult of 64).
  f16 *W16_e1f = nullptr, *W16_e1b = nullptr;
  f16 *W16_e0f = nullptr, *W16_e0b = nullptr;
  f16 *W16_dec = nullptr;
  auto try_allocw = [&](size_t elts) -> f16* {
    size_t o = (off + 255) & ~(size_t)255;
    if (o + elts * 2 > ws_size) return nullptr;
    off = o + elts * 2;
    return (f16*)(wsp + o);
  };
  {
    const size_t e1e = (size_t)3 * Hn * 3072;   // KWP(2048+1024)=3072
    const size_t e0e = (size_t)3 * Hn * 1152;   // KWP(96+1024)=1152
    const size_t dce = (size_t)3 * Hn * 1216;   // KWP(192+1024)=1216
    size_t save = off;
    f16* a1 = try_allocw(e1e); f16* b1 = a1 ? try_allocw(e1e) : nullptr;
    if (b1) { W16_e1f = a1; W16_e1b = b1; } else off = save;
    save = off;
    f16* a0 = try_allocw(e0e); f16* b0 = a0 ? try_allocw(e0e) : nullptr;
    if (b0) { W16_e0f = a0; W16_e0b = b0; } else off = save;
    save = off;
    f16* dc = try_allocw(dce);
    if (dc) W16_dec = dc; else off = save;
  }
  if (W16_e1f) {
    wconvert<<<dim3(3072), dim3(256), 0, stream>>>(
        (const float*)d_in[11], (const float*)d_in[12], 2048, 3072, W16_e1f);
    wconvert<<<dim3(3072), dim3(256), 0, stream>>>(
        (const float*)d_in[15], (const float*)d_in[16], 2048, 3072, W16_e1b);
  }
  if (W16_e0f) {
    wconvert<<<dim3(3072), dim3(256), 0, stream>>>(
        (const float*)d_in[3], (const float*)d_in[4], Cn, 1152, W16_e0f);
    wconvert<<<dim3(3072), dim3(256), 0, stream>>>(
        (const float*)d_in[7], (const float*)d_in[8], Cn, 1152, W16_e0b);
  }
  if (W16_dec)
    wconvert<<<dim3(3072), dim3(256), 0, stream>>>(
        (const float*)d_in[28], (const float*)d_in[29], 192, 1216, W16_dec);

  init_kernel<<<dim3(512), dim3(256), 0, stream>>>(
      hf[0][0], hf[1][0], hf[2][0], hf[3][0],
      hh[0][0], hh[1][0], hh[2][0], hh[3][0],
      xdec, (const float*)d_in[27]);
  melody_fill<<<dim3((MELn / 4 + 255) / 256, Bn), dim3(256), 0, stream>>>(
      (const float*)d_in[1], zcat);

  const int* lenp = (const int*)d_in[34];

  // ---- encoder layer 0 (bidirectional, fused fwd+bwd per launch) ----
  for (int s = 0; s < Tn; ++s) {
    StepArgs a{};
    const int tf = s, tb = Tn - 1 - s;
    const int p = s & 1, q = (s + 1) & 1;
    a.d[0].x = (const float*)d_in[0] + (size_t)tf * Cn;
    a.d[0].Wih = (const float*)d_in[3]; a.d[0].Whh = (const float*)d_in[4];
    a.d[0].bih = (const float*)d_in[5]; a.d[0].bhh = (const float*)d_in[6];
    a.d[0].W16 = W16_e0f;
    a.d[0].hprev_f = hf[0][p]; a.d[0].hprev_h = hh[0][p];
    a.d[0].hcur_f = hf[0][q]; a.d[0].hcur_h = hh[0][q];
    a.d[0].yout = y0 + (size_t)tf * Bn * 2048 * esz;
    a.d[0].t = tf;
    a.d[1].x = (const float*)d_in[0] + (size_t)tb * Cn;
    a.d[1].Wih = (const float*)d_in[7]; a.d[1].Whh = (const float*)d_in[8];
    a.d[1].bih = (const float*)d_in[9]; a.d[1].bhh = (const float*)d_in[10];
    a.d[1].W16 = W16_e0b;
    a.d[1].hprev_f = hf[1][p]; a.d[1].hprev_h = hh[1][p];
    a.d[1].hcur_f = hf[1][q]; a.d[1].hcur_h = hh[1][q];
    a.d[1].yout = y0 + ((size_t)tb * Bn * 2048 + Hn) * esz;
    a.d[1].t = tb;
    a.length = lenp;
    a.xs = Tn * Cn;   // input_x is (B,T,C): batch stride T*C
    if (y16) {
      if (W16_e0f) gru_step_kernel<Cn, 1, 1, 1><<<dim3(32, 4, 2), dim3(512), 0, stream>>>(a);
      else         gru_step_kernel<Cn, 1, 1, 0><<<dim3(32, 4, 2), dim3(256), 0, stream>>>(a);
    } else {
      if (W16_e0f) gru_step_kernel<Cn, 1, 2, 1><<<dim3(32, 4, 2), dim3(512), 0, stream>>>(a);
      else         gru_step_kernel<Cn, 1, 2, 0><<<dim3(32, 4, 2), dim3(256), 0, stream>>>(a);
    }
  }
  // ---- encoder layer 1 ----
  for (int s = 0; s < Tn; ++s) {
    StepArgs a{};
    const int tf = s, tb = Tn - 1 - s;
    const int p = s & 1, q = (s + 1) & 1;
    a.d[0].x = y0 + (size_t)tf * Bn * 2048 * esz;
    a.d[0].Wih = (const float*)d_in[11]; a.d[0].Whh = (const float*)d_in[12];
    a.d[0].bih = (const float*)d_in[13]; a.d[0].bhh = (const float*)d_in[14];
    a.d[0].W16 = W16_e1f;
    a.d[0].hprev_f = hf[2][p]; a.d[0].hprev_h = hh[2][p];
    a.d[0].hcur_f = hf[2][q]; a.d[0].hcur_h = hh[2][q];
    a.d[0].yout = nullptr;
    a.d[0].t = tf;
    a.d[1].x = y0 + (size_t)tb * Bn * 2048 * esz;
    a.d[1].Wih = (const float*)d_in[15]; a.d[1].Whh = (const float*)d_in[16];
    a.d[1].bih = (const float*)d_in[17]; a.d[1].bhh = (const float*)d_in[18];
    a.d[1].W16 = W16_e1b;
    a.d[1].hprev_f = hf[3][p]; a.d[1].hprev_h = hh[3][p];
    a.d[1].hcur_f = hf[3][q]; a.d[1].hcur_h = hh[3][q];
    a.d[1].yout = nullptr;
    a.d[1].t = tb;
    a.length = lenp;
    a.xs = 2048;
    if (y16) {
      if (W16_e1f) gru_step_kernel<2048, 0, 0, 1><<<dim3(32, 4, 2), dim3(512), 0, stream>>>(a);
      else         gru_step_kernel<2048, 0, 0, 0><<<dim3(32, 4, 2), dim3(256), 0, stream>>>(a);
    } else {
      if (W16_e1f) gru_step_kernel<2048, 2, 0, 1><<<dim3(32, 4, 2), dim3(512), 0, stream>>>(a);
      else         gru_step_kernel<2048, 2, 0, 0><<<dim3(32, 4, 2), dim3(256), 0, stream>>>(a);
    }
  }

  // ---- VAE mid-section ----
  build_hid<<<dim3((Bn * Hn + 255) / 256), dim3(256), 0, stream>>>(
      hh[0][0], hh[1][0], hh[2][0], hh[3][0], hidf);
  gemm_nt_kernel<<<dim3(8, 4), dim3(256), 0, stream>>>(
      hidf, (const float*)d_in[19], (const float*)d_in[21],
      (const float*)d_in[20], (const float*)d_in[22], 256, mulv_f, 512, 4096);
  float* outp = (float*)d_out;
  z_kernel<<<dim3((Bn * Ln + 255) / 256), dim3(256), 0, stream>>>(
      mulv_f, (const float*)d_in[2], zcat,
      outp + 2 * (size_t)OUT_SM, outp + 2 * (size_t)OUT_SM + Bn * Ln);
  gemm_nt_kernel<<<dim3(18, 4), dim3(256), 0, stream>>>(
      zcat, (const float*)d_in[23], (const float*)d_in[25],
      (const float*)d_in[24], (const float*)d_in[26], 96, zres_f, 1120, ZDn);
  zscatter<<<dim3((Bn * 1120 + 255) / 256), dim3(256), 0, stream>>>(
      zres_f, xdec, hf[4][0], hh[4][0]);

  // ---- autoregressive decoder ----
  for (int s = 0; s < Tn; ++s) {
    StepArgs a{};
    const int p = s & 1, q = (s + 1) & 1;
    a.d[0].x = xdec;
    a.d[0].Wih = (const float*)d_in[28]; a.d[0].Whh = (const float*)d_in[29];
    a.d[0].bih = (const float*)d_in[30]; a.d[0].bhh = (const float*)d_in[31];
    a.d[0].W16 = W16_dec;
    a.d[0].hprev_f = hf[4][p]; a.d[0].hprev_h = hh[4][p];
    a.d[0].hcur_f = hf[4][q]; a.d[0].hcur_h = hh[4][q];
    a.d[0].yout = nullptr;
    a.d[0].t = s;
    a.d[1] = a.d[0];
    a.length = nullptr;  // decoder: no masking
    a.xs = 192;
    if (W16_dec) gru_step_kernel<192, 0, 0, 1><<<dim3(32, 4, 1), dim3(512), 0, stream>>>(a);
    else         gru_step_kernel<192, 0, 0, 0><<<dim3(32, 4, 1), dim3(256), 0, stream>>>(a);
    outproj_kernel<<<dim3(Bn), dim3(256), 0, stream>>>(
        hf[4][q], (const float*)d_in[32], (const float*)d_in[33],
        outp, xdec, s);
  }

  softmax_kernel<<<dim3((Bn * Tn + 3) / 4), dim3(256), 0, stream>>>(outp);
}